// Round 1
// baseline (512.935 us; speedup 1.0000x reference)
//
#include <hip/hip_runtime.h>
#include <hip/hip_bf16.h>

#define ENC_DIM 2048
#define DEC_DIM 512
#define ATT_DIM 512
#define BATCH   128
#define NPIX    196
#define NROWS   (BATCH * NPIX)   // 25088

typedef short bf16x8 __attribute__((ext_vector_type(8)));
typedef float f32x4  __attribute__((ext_vector_type(4)));

__device__ __forceinline__ unsigned short f2bf(float f) {
    union { float f; unsigned u; } v; v.f = f;
    unsigned r = v.u + 0x7fffu + ((v.u >> 16) & 1u);   // RNE
    return (unsigned short)(r >> 16);
}

// ---------------------------------------------------------------- k0:
// Wt[a][e] = bf16(W_enc[e][a])  (2048x512 -> 512x2048), LDS-tiled transpose.
__global__ void k0_transpose(const float* __restrict__ W_enc,
                             unsigned short* __restrict__ Wt) {
    __shared__ float ts[64][65];
    const int a0 = blockIdx.x * 64;      // grid.x = 8
    const int e0 = blockIdx.y * 64;      // grid.y = 32
    const int tx = threadIdx.x & 15;
    const int ty = threadIdx.x >> 4;     // 16x16 threads
    #pragma unroll
    for (int p = 0; p < 4; ++p) {
        const int e = ty + p * 16;
        const float4 v = *(const float4*)&W_enc[(size_t)(e0 + e) * ATT_DIM + a0 + tx * 4];
        ts[e][tx * 4 + 0] = v.x; ts[e][tx * 4 + 1] = v.y;
        ts[e][tx * 4 + 2] = v.z; ts[e][tx * 4 + 3] = v.w;
    }
    __syncthreads();
    #pragma unroll
    for (int p = 0; p < 4; ++p) {
        const int a = ty + p * 16;
        ushort4 u;
        u.x = f2bf(ts[tx * 4 + 0][a]);
        u.y = f2bf(ts[tx * 4 + 1][a]);
        u.z = f2bf(ts[tx * 4 + 2][a]);
        u.w = f2bf(ts[tx * 4 + 3][a]);
        *(ushort4*)&Wt[(size_t)(a0 + a) * ENC_DIM + e0 + tx * 4] = u;
    }
}

// ---------------------------------------------------------------- k1:
// att2'[b][a] = dh[b,:]@W_dec[:,a] + b_dec[a] + b_enc[a];  also att[r]=b_full.
__global__ void k1_att2(const float* __restrict__ dh, const float* __restrict__ W_dec,
                        const float* __restrict__ b_dec, const float* __restrict__ b_enc,
                        const float* __restrict__ b_full,
                        float* __restrict__ att2, float* __restrict__ att) {
    __shared__ float dhs[DEC_DIM];
    const int b = blockIdx.x, t = threadIdx.x;   // 128 blocks x 256 thr
    dhs[t]       = dh[b * DEC_DIM + t];
    dhs[t + 256] = dh[b * DEC_DIM + t + 256];
    __syncthreads();
    float acc0 = 0.f, acc1 = 0.f;
    for (int d = 0; d < DEC_DIM; ++d) {
        const float h = dhs[d];
        acc0 += h * W_dec[d * ATT_DIM + t];
        acc1 += h * W_dec[d * ATT_DIM + t + 256];
    }
    att2[b * ATT_DIM + t]       = acc0 + b_dec[t]       + b_enc[t];
    att2[b * ATT_DIM + t + 256] = acc1 + b_dec[t + 256] + b_enc[t + 256];
    const int gid = b * 256 + t;
    if (gid < NROWS) att[gid] = b_full[0];
}

// ---------------------------------------------------------------- k2:
// Fused bf16 MFMA GEMM + relu + W_full reduction -> atomic partial scores.
// Tile 128 rows x 128 attn-cols, K-chunks of 32. grid (4 n-tiles, 196 m-tiles).
__launch_bounds__(256, 2)
__global__ void k2_gemm(const float* __restrict__ enc, const unsigned short* __restrict__ Wt,
                        const float* __restrict__ att2, const float* __restrict__ W_full,
                        float* __restrict__ att) {
    __shared__ unsigned short As[128 * 40];   // rows padded to 40 bf16 (80 B)
    __shared__ unsigned short Bs[128 * 40];
    __shared__ float att2s[2][128];
    __shared__ float wfs[128];

    const int t    = threadIdx.x;
    const int n0   = blockIdx.x * 128;
    const int row0 = blockIdx.y * 128;
    const int b0   = row0 / NPIX;
    const int rows_left = (b0 + 1) * NPIX - row0;   // rows in this tile with batch b0

    if (t < 128) {
        att2s[0][t] = att2[b0 * ATT_DIM + n0 + t];
        att2s[1][t] = (b0 + 1 < BATCH) ? att2[(b0 + 1) * ATT_DIM + n0 + t] : 0.f;
        wfs[t]      = W_full[n0 + t];
    }

    const int w    = t >> 6;         // wave 0..3
    const int lane = t & 63;
    const int q    = lane >> 4;      // 0..3
    const int cl   = lane & 15;
    const int wm   = (w >> 1) * 64;  // wave's row offset
    const int wn   = (w & 1) * 64;   // wave's col offset

    f32x4 acc[4][4] = {};

    const int a_mr = t >> 3;          // 0..31 (+32 per pass)
    const int a_kk = (t & 7) * 4;     // 0..28
    const int b_nc = t >> 2;          // 0..63 (+64 per pass)
    const int b_kq = (t & 3) * 8;     // 0,8,16,24

    const float*          encA = enc + (size_t)(row0 + a_mr) * ENC_DIM + a_kk;
    const unsigned short* WtB  = Wt  + (size_t)(n0 + b_nc)   * ENC_DIM + b_kq;

    for (int k0 = 0; k0 < ENC_DIM; k0 += 32) {
        // stage A (fp32 -> bf16), 128x32
        #pragma unroll
        for (int p = 0; p < 4; ++p) {
            const float4 v = *(const float4*)(encA + (size_t)p * 32 * ENC_DIM + k0);
            ushort4 u;
            u.x = f2bf(v.x); u.y = f2bf(v.y); u.z = f2bf(v.z); u.w = f2bf(v.w);
            *(ushort4*)&As[(a_mr + p * 32) * 40 + a_kk] = u;
        }
        // stage B (already bf16), 128x32
        #pragma unroll
        for (int p = 0; p < 2; ++p) {
            const uint4 v = *(const uint4*)(WtB + (size_t)p * 64 * ENC_DIM + k0);
            *(uint4*)&Bs[(b_nc + p * 64) * 40 + b_kq] = v;
        }
        __syncthreads();

        bf16x8 af[4], bfr[4];
        #pragma unroll
        for (int i = 0; i < 4; ++i) {
            af[i]  = *(const bf16x8*)&As[(wm + i * 16 + cl) * 40 + q * 8];
            bfr[i] = *(const bf16x8*)&Bs[(wn + i * 16 + cl) * 40 + q * 8];
        }
        #pragma unroll
        for (int mi = 0; mi < 4; ++mi)
            #pragma unroll
            for (int ni = 0; ni < 4; ++ni)
                acc[mi][ni] = __builtin_amdgcn_mfma_f32_16x16x32_bf16(
                    af[mi], bfr[ni], acc[mi][ni], 0, 0, 0);
        __syncthreads();
    }

    // Epilogue: relu(att1 + att2') * W_full, reduce over this block's 128 cols.
    #pragma unroll
    for (int mi = 0; mi < 4; ++mi) {
        float rs[4];
        #pragma unroll
        for (int i = 0; i < 4; ++i) {
            const int lr  = wm + mi * 16 + q * 4 + i;         // local row
            const int sel = (lr >= rows_left) ? 1 : 0;
            float sum = 0.f;
            #pragma unroll
            for (int ni = 0; ni < 4; ++ni) {
                const int j = wn + ni * 16 + cl;              // local col 0..127
                float v = acc[mi][ni][i] + att2s[sel][j];
                v = fmaxf(v, 0.f);
                sum += v * wfs[j];
            }
            rs[i] = sum;
        }
        #pragma unroll
        for (int o = 1; o < 16; o <<= 1) {
            #pragma unroll
            for (int i = 0; i < 4; ++i) rs[i] += __shfl_xor(rs[i], o);
        }
        if (cl == 0) {
            #pragma unroll
            for (int i = 0; i < 4; ++i) {
                const int r = row0 + wm + mi * 16 + q * 4 + i;
                atomicAdd(&att[r], rs[i]);
            }
        }
    }
}

// ---------------------------------------------------------------- k3:
// softmax over P=196, in place. 128 blocks x 256 thr.
__global__ void k3_softmax(float* __restrict__ att_alpha) {
    __shared__ float red[4];
    const int b = blockIdx.x, t = threadIdx.x;
    const int w = t >> 6, lane = t & 63;
    const float x = (t < NPIX) ? att_alpha[b * NPIX + t] : -INFINITY;
    float m = x;
    #pragma unroll
    for (int o = 32; o >= 1; o >>= 1) m = fmaxf(m, __shfl_xor(m, o));
    if (lane == 0) red[w] = m;
    __syncthreads();
    m = fmaxf(fmaxf(red[0], red[1]), fmaxf(red[2], red[3]));
    const float e = (t < NPIX) ? __expf(x - m) : 0.f;
    float s = e;
    #pragma unroll
    for (int o = 32; o >= 1; o >>= 1) s += __shfl_xor(s, o);
    __syncthreads();
    if (lane == 0) red[w] = s;
    __syncthreads();
    s = red[0] + red[1] + red[2] + red[3];
    if (t < NPIX) att_alpha[b * NPIX + t] = e / s;
}

// ---------------------------------------------------------------- k4:
// awe[b][e] = sum_p alpha[b][p] * enc[b][p][e].  grid (2 e-chunks, 128 b).
__global__ void k4_awe(const float* __restrict__ enc, const float* __restrict__ alpha,
                       float* __restrict__ awe) {
    __shared__ float as[NPIX];
    const int b  = blockIdx.y;
    const int e0 = blockIdx.x * 1024 + threadIdx.x * 4;
    if (threadIdx.x < NPIX) as[threadIdx.x] = alpha[b * NPIX + threadIdx.x];
    __syncthreads();
    f32x4 a0 = {0,0,0,0}, a1 = {0,0,0,0}, a2 = {0,0,0,0}, a3 = {0,0,0,0};
    const float* base = enc + (size_t)b * NPIX * ENC_DIM + e0;
    for (int p = 0; p < NPIX; p += 4) {
        const f32x4 v0 = *(const f32x4*)(base + (size_t)(p + 0) * ENC_DIM);
        const f32x4 v1 = *(const f32x4*)(base + (size_t)(p + 1) * ENC_DIM);
        const f32x4 v2 = *(const f32x4*)(base + (size_t)(p + 2) * ENC_DIM);
        const f32x4 v3 = *(const f32x4*)(base + (size_t)(p + 3) * ENC_DIM);
        a0 += as[p + 0] * v0; a1 += as[p + 1] * v1;
        a2 += as[p + 2] * v2; a3 += as[p + 3] * v3;
    }
    const f32x4 r = (a0 + a1) + (a2 + a3);
    *(f32x4*)&awe[(size_t)b * ENC_DIM + e0] = r;
}

// ----------------------------------------------------------------
extern "C" void kernel_launch(void* const* d_in, const int* in_sizes, int n_in,
                              void* d_out, int out_size, void* d_ws, size_t ws_size,
                              hipStream_t stream) {
    const float* enc    = (const float*)d_in[0];   // [128,196,2048]
    const float* dh     = (const float*)d_in[1];   // [128,512]
    const float* W_enc  = (const float*)d_in[2];   // [2048,512]
    const float* b_enc  = (const float*)d_in[3];   // [512]
    const float* W_dec  = (const float*)d_in[4];   // [512,512]
    const float* b_dec  = (const float*)d_in[5];   // [512]
    const float* W_full = (const float*)d_in[6];   // [512]
    const float* b_full = (const float*)d_in[7];   // scalar

    float* awe   = (float*)d_out;                  // [128,2048]
    float* alpha = awe + BATCH * ENC_DIM;          // [128,196]; also score scratch

    // workspace: Wt bf16 (2 MB) + att2' fp32 (256 KB) = 2.25 MB
    unsigned short* Wt   = (unsigned short*)d_ws;
    float*          att2 = (float*)((char*)d_ws + (size_t)ATT_DIM * ENC_DIM * 2);

    k0_transpose<<<dim3(8, 32),  256, 0, stream>>>(W_enc, Wt);
    k1_att2     <<<128,          256, 0, stream>>>(dh, W_dec, b_dec, b_enc, b_full, att2, alpha);
    k2_gemm     <<<dim3(4, 196), 256, 0, stream>>>(enc, Wt, att2, W_full, alpha);
    k3_softmax  <<<128,          256, 0, stream>>>(alpha);
    k4_awe      <<<dim3(2, 128), 256, 0, stream>>>(enc, alpha, awe);
}